// Round 7
// baseline (153.993 us; speedup 1.0000x reference)
//
#include <hip/hip_runtime.h>
#include <stdint.h>

// y[n,i] = relu(b[idx[n],i] + sum_o w[idx[n],i,o] * x[n,o])
// B=8192, 64 models, 256x256 fp32.
//
// R7 = R6 (fused compaction + global_load_lds w-pipeline + lgkm-only scan
// barriers) wrapped in REPEAT=8, byte-identical otherwise. Diagnostic: the
// single-shot metric is pinned at 86+-1 for every structure tried; this
// surfaces the R6 kernel's own dispatch (cold rep + 7 warm reps) above the
// 43us harness fills so we can read warm-vs-cold and FETCH/VALU/Mfma for
// the DMA structure and pick the next lever per the pre-committed tree.
// Cross-rep races are value-identical rewrites (w/x/rid same data each rep);
// rid=-1 transients only skip stores in reps<7; rep 7 is barrier-ordered and
// race-clean -> exact output.

#define N_MODELS 64
#define IN_F     256
#define OUT_F    256
#define BATCH    8192
#define BM       128
#define BN       128
#define PKX      264   // x LDS pitch bf16: 256+8
#define REPEAT   8     // diagnostic multiplier

typedef __bf16 bf16x8 __attribute__((ext_vector_type(8)));
typedef float  f32x4  __attribute__((ext_vector_type(4)));
typedef __attribute__((address_space(3))) uint32_t lds_u32;
typedef const __attribute__((address_space(1))) uint32_t glb_u32;

__device__ __forceinline__ void dma16(const void* g, void* l) {
  __builtin_amdgcn_global_load_lds((glb_u32*)g, (lds_u32*)l, 16, 0, 0);
}

// raw block barrier that waits LDS ops only -> w DMA (vmcnt) stays in flight
__device__ __forceinline__ void barrier_lds_only() {
  asm volatile("s_waitcnt lgkmcnt(0)" ::: "memory");
  __builtin_amdgcn_s_barrier();
  __builtin_amdgcn_sched_barrier(0);   // no hoisting of post-barrier LDS reads
}

__device__ __forceinline__ bf16x8 pack8(float4 a, float4 b) {
  bf16x8 o;                       // native casts -> v_cvt_pk_bf16_f32
  o[0] = (__bf16)a.x; o[1] = (__bf16)a.y; o[2] = (__bf16)a.z; o[3] = (__bf16)a.w;
  o[4] = (__bf16)b.x; o[5] = (__bf16)b.y; o[6] = (__bf16)b.z; o[7] = (__bf16)b.w;
  return o;
}

__global__ __launch_bounds__(1024) void fused_kernel(
    const float* __restrict__ x, const int* __restrict__ idxs,
    const float* __restrict__ w, const float* __restrict__ bias_g,
    float* __restrict__ out) {
  // XCD-bijective swizzle (256 % 8 == 0): a model's 4 blocks -> one XCD
  const int b     = (blockIdx.x & 7) * 32 + (blockIdx.x >> 3);
  const int model = b >> 2;
  const int s     = (b >> 1) & 1;    // sample-tile (rows s*128 ..)
  const int i0    = (b & 1) * BN;    // out-col tile
  const int t     = threadIdx.x;
  const int lane  = t & 63;
  const int wv    = t >> 6;          // 0..15

  __shared__ float w_lds[2][BM][64];        // quarter-K f32, dbuf, DMA dest
  __shared__ unsigned short a_lds[BM][PKX]; // gathered x rows, bf16, full K
  __shared__ int rid[BM];
  __shared__ int wsum[16];

  const float* wbase = w + (size_t)model * (IN_F * OUT_F) + (size_t)i0 * IN_F;
  const int l_r = lane >> 4;         // row within the 4-row group
  const int l_c = lane & 15;         // 16B chunk within the row
#define W_DMA(q, buf)                                                        \
  {                                                                          \
    _Pragma("unroll")                                                        \
    for (int j = 0; j < 2; ++j) {                                            \
      const int r0 = wv * 8 + j * 4;                                         \
      const int rr = r0 + l_r;                                               \
      const float* gs = wbase + (size_t)rr * IN_F + (q) * 64                 \
                        + ((l_c ^ (rr & 7)) << 2);                           \
      dma16(gs, &w_lds[buf][r0][0]);                                         \
    }                                                                        \
  }

  // wave tile coords (loop-invariant)
  const int wm   = (wv & 3) * 32;    // 4x4 wave grid of 32x32 tiles
  const int wn   = (wv >> 2) * 32;
  const int col  = lane & 15;
  const int quad = lane >> 4;

  for (int rep = 0; rep < REPEAT; ++rep) {
    asm volatile("" ::: "memory");   // no cross-rep CSE/hoist of loads

    // ---- idx loads FIRST (scan critical path; in-order vmcnt) ----
    const int4* ip = (const int4*)idxs + t * 2;   // 8 idxs/thread
    int4 iv0 = ip[0], iv1 = ip[1];

    // s==0 blocks never early-exit: issue q0+q1 now
    if (s == 0) { W_DMA(0, 0) W_DMA(1, 1) }

    if (t < BM) rid[t] = -1;

    // ---- compaction: thread t owns idxs[8t .. 8t+7] ----
    int cnt = (iv0.x == model) + (iv0.y == model) + (iv0.z == model) + (iv0.w == model)
            + (iv1.x == model) + (iv1.y == model) + (iv1.z == model) + (iv1.w == model);
    int inc = cnt;
#pragma unroll
    for (int d = 1; d < 64; d <<= 1) {
      int u = __shfl_up(inc, d);
      if (lane >= d) inc += u;
    }
    if (lane == 63) wsum[wv] = inc;
    barrier_lds_only();              // RAW-BAR-1: wsum + rid(-1) committed
    int wpre = 0, total = 0;
#pragma unroll
    for (int j = 0; j < 16; ++j) {
      int sj = wsum[j];
      total += sj;
      if (j < wv) wpre += sj;
    }
    const int start = s * BM;
    if (start >= total) break;       // block-uniform (only s==1 can exit)
    if (s == 1) { W_DMA(0, 0) W_DMA(1, 1) }

    int off = wpre + inc - cnt - start;
    {
      int n0 = t * 8;
      if (iv0.x == model) { if ((unsigned)off < BM) rid[off] = n0 + 0; ++off; }
      if (iv0.y == model) { if ((unsigned)off < BM) rid[off] = n0 + 1; ++off; }
      if (iv0.z == model) { if ((unsigned)off < BM) rid[off] = n0 + 2; ++off; }
      if (iv0.w == model) { if ((unsigned)off < BM) rid[off] = n0 + 3; ++off; }
      if (iv1.x == model) { if ((unsigned)off < BM) rid[off] = n0 + 4; ++off; }
      if (iv1.y == model) { if ((unsigned)off < BM) rid[off] = n0 + 5; ++off; }
      if (iv1.z == model) { if ((unsigned)off < BM) rid[off] = n0 + 6; ++off; }
      if (iv1.w == model) { if ((unsigned)off < BM) rid[off] = n0 + 7; ++off; }
    }
    barrier_lds_only();              // RAW-BAR-2: rid ready (DMA untouched)

    // ---- x staging (gathered rows; invalid rows read row 0) ----
    const int rwx = t >> 3;          // x staged row (8 thr/row), 0..127
    const int hx  = t & 7;           // 32-float chunk
    const int srow = rid[rwx];
    const float* xrow = x + (size_t)(srow < 0 ? 0 : srow) * IN_F + hx * 32;
    {
      float4 tx[8];
#pragma unroll
      for (int j = 0; j < 8; ++j) tx[j] = *(const float4*)(xrow + j * 4);
#pragma unroll
      for (int j = 0; j < 4; ++j)
        *(bf16x8*)&a_lds[rwx][hx * 32 + j * 8] = pack8(tx[2 * j], tx[2 * j + 1]);
    }

    // bias (issued while staging drains)
    float bv[2];
    const float* bp = bias_g + model * OUT_F + i0 + wn + col;
#pragma unroll
    for (int nt = 0; nt < 2; ++nt) bv[nt] = bp[nt * 16];

    __syncthreads();                 // B1: full drain = q0,q1 + a_lds ready

    f32x4 acc[2][2];                 // bias folded into acc init
#pragma unroll
    for (int mt = 0; mt < 2; ++mt)
#pragma unroll
      for (int nt = 0; nt < 2; ++nt)
        acc[mt][nt] = (f32x4){bv[nt], bv[nt], bv[nt], bv[nt]};

#define MFMA_QUARTER(buf, ks0)                                               \
  {                                                                          \
    _Pragma("unroll")                                                        \
    for (int kk = 0; kk < 2; ++kk) {                                         \
      const int ks  = (ks0) + kk;                                            \
      const int ch0 = kk * 8 + quad * 2;                                     \
      bf16x8 af[2], bfr[2];                                                  \
      _Pragma("unroll")                                                      \
      for (int mt = 0; mt < 2; ++mt)                                         \
        af[mt] = *(const bf16x8*)&a_lds[wm + mt * 16 + col]                  \
                                      [ks * 32 + quad * 8];                  \
      _Pragma("unroll")                                                      \
      for (int nt = 0; nt < 2; ++nt) {                                       \
        const int R  = wn + nt * 16 + col;                                   \
        const int sw = R & 7;                                                \
        float4 f0 = *(const float4*)&w_lds[buf][R][((ch0)     ^ sw) << 2];   \
        float4 f1 = *(const float4*)&w_lds[buf][R][((ch0 + 1) ^ sw) << 2];   \
        bfr[nt] = pack8(f0, f1);                                             \
      }                                                                      \
      _Pragma("unroll")                                                      \
      for (int mt = 0; mt < 2; ++mt)                                         \
        _Pragma("unroll")                                                    \
        for (int nt = 0; nt < 2; ++nt)                                       \
          acc[mt][nt] = __builtin_amdgcn_mfma_f32_16x16x32_bf16(             \
              af[mt], bfr[nt], acc[mt][nt], 0, 0, 0);                        \
    }                                                                        \
  }

    MFMA_QUARTER(0, 0)               // q0
    __syncthreads();                 // B2: buf0 reads done
    W_DMA(2, 0)                      // refill buf0 (overlaps q1 mfma)
    MFMA_QUARTER(1, 2)               // q1
    __syncthreads();                 // B3: drains q2 DMA; buf1 reads done
    W_DMA(3, 1)                      // refill buf1 (overlaps q2 mfma)
    MFMA_QUARTER(0, 4)               // q2
    __syncthreads();                 // B4: drains q3 DMA
    MFMA_QUARTER(1, 6)               // q3

    // ---- epilogue: relu + scatter by sample id ----
#pragma unroll
    for (int mt = 0; mt < 2; ++mt) {
#pragma unroll
      for (int reg = 0; reg < 4; ++reg) {
        const int mm = wm + mt * 16 + quad * 4 + reg;   // C/D: row = quad*4+reg
        const int sle = rid[mm];
        if (sle >= 0) {
          float* orow = out + (size_t)sle * OUT_F + i0 + wn + col;
#pragma unroll
          for (int nt = 0; nt < 2; ++nt)
            orow[nt * 16] = fmaxf(acc[mt][nt][reg], 0.0f);
        }
      }
    }
#undef MFMA_QUARTER
  }
#undef W_DMA
}

extern "C" void kernel_launch(void* const* d_in, const int* in_sizes, int n_in,
                              void* d_out, int out_size, void* d_ws, size_t ws_size,
                              hipStream_t stream) {
  const float* x    = (const float*)d_in[0];
  const int*   idxs = (const int*)d_in[1];
  const float* w    = (const float*)d_in[2];
  const float* b    = (const float*)d_in[3];
  float* out = (float*)d_out;
  (void)d_ws; (void)ws_size;

  fused_kernel<<<N_MODELS * 4, 1024, 0, stream>>>(x, idxs, w, b, out);
}

// Round 8
// 83.113 us; speedup vs baseline: 1.8528x; 1.8528x over previous
//
#include <hip/hip_runtime.h>
#include <stdint.h>

// y[n,i] = relu(b[idx[n],i] + sum_o w[idx[n],i,o] * x[n,o])
// B=8192, 64 models, 256x256 fp32.
//
// R8: fully-DMA pipeline. Fused compaction (lgkm-only scan barriers keep DMA
// in flight) + BOTH streams staged f32 via global_load_lds quarter-K double
// buffers (w 2x32KB + x 2x32KB = 128KB LDS):
//  - w q0+q1 issued at t0 (s==0; s==1 after proving non-empty).
//  - x q0+q1 issued right after rid is ready: per-lane global src =
//    x[rid[row]] + XOR-swizzled 16B chunk, LDS dest wave-linear (HW rule).
//    Replaces the old reg-staged gather (8 float4 loads + 16 cvt_pk + 4
//    ds_writes per thread) with 2 LDS reads + 2 dma16 -> the last serial
//    staging phase collapses; ~32 VGPR freed.
//  - A and B MFMA fragments both read f32 from LDS with the same XOR-chunk
//    swizzle + pack8 on the fly (R5/R6-verified pattern).
//  - B1..B4 plain __syncthreads: vmcnt drain == refill-completion guarantee.
// 256 blocks (64 models x 2 sample-tiles x 2 out-tiles), 1024 thr, 16 waves
// 4x4 grid of 32x32 tiles, XCD-bijective swizzle.

#define N_MODELS 64
#define IN_F     256
#define OUT_F    256
#define BATCH    8192
#define BM       128
#define BN       128

typedef __bf16 bf16x8 __attribute__((ext_vector_type(8)));
typedef float  f32x4  __attribute__((ext_vector_type(4)));
typedef __attribute__((address_space(3))) uint32_t lds_u32;
typedef const __attribute__((address_space(1))) uint32_t glb_u32;

__device__ __forceinline__ void dma16(const void* g, void* l) {
  __builtin_amdgcn_global_load_lds((glb_u32*)g, (lds_u32*)l, 16, 0, 0);
}

// raw block barrier that waits LDS ops only -> in-flight DMA survives
__device__ __forceinline__ void barrier_lds_only() {
  asm volatile("s_waitcnt lgkmcnt(0)" ::: "memory");
  __builtin_amdgcn_s_barrier();
  __builtin_amdgcn_sched_barrier(0);
}

__device__ __forceinline__ bf16x8 pack8(float4 a, float4 b) {
  bf16x8 o;                       // native casts -> v_cvt_pk_bf16_f32
  o[0] = (__bf16)a.x; o[1] = (__bf16)a.y; o[2] = (__bf16)a.z; o[3] = (__bf16)a.w;
  o[4] = (__bf16)b.x; o[5] = (__bf16)b.y; o[6] = (__bf16)b.z; o[7] = (__bf16)b.w;
  return o;
}

__global__ __launch_bounds__(1024) void fused_kernel(
    const float* __restrict__ x, const int* __restrict__ idxs,
    const float* __restrict__ w, const float* __restrict__ bias_g,
    float* __restrict__ out) {
  // XCD-bijective swizzle (256 % 8 == 0): a model's 4 blocks -> one XCD
  const int b     = (blockIdx.x & 7) * 32 + (blockIdx.x >> 3);
  const int model = b >> 2;
  const int s     = (b >> 1) & 1;    // sample-tile (rows s*128 ..)
  const int i0    = (b & 1) * BN;    // out-col tile
  const int t     = threadIdx.x;
  const int lane  = t & 63;
  const int wv    = t >> 6;          // 0..15

  __shared__ float w_lds[2][BM][64];   // w quarter-K f32, dbuf, DMA dest
  __shared__ float x_lds[2][BM][64];   // x quarter-K f32, dbuf, DMA dest
  __shared__ int rid[BM];
  __shared__ int wsum[16];

  const float* wbase = w + (size_t)model * (IN_F * OUT_F) + (size_t)i0 * IN_F;
  const int l_r = lane >> 4;         // row within the 4-row group
  const int l_c = lane & 15;         // 16B chunk within the row
#define W_DMA(q, buf)                                                        \
  {                                                                          \
    _Pragma("unroll")                                                        \
    for (int j = 0; j < 2; ++j) {                                            \
      const int r0 = wv * 8 + j * 4;                                         \
      const int rr = r0 + l_r;                                               \
      const float* gs = wbase + (size_t)rr * IN_F + (q) * 64                 \
                        + ((l_c ^ (rr & 7)) << 2);                           \
      dma16(gs, &w_lds[buf][r0][0]);                                         \
    }                                                                        \
  }

  // ---- idx loads FIRST (scan critical path; in-order vmcnt) ----
  const int4* ip = (const int4*)idxs + t * 2;   // 8 idxs/thread
  int4 iv0 = ip[0], iv1 = ip[1];

  // s==0 blocks never early-exit: put w q0+q1 in flight at t0
  if (s == 0) { W_DMA(0, 0) W_DMA(1, 1) }

  if (t < BM) rid[t] = -1;

  // ---- compaction: thread t owns idxs[8t .. 8t+7] ----
  int cnt = (iv0.x == model) + (iv0.y == model) + (iv0.z == model) + (iv0.w == model)
          + (iv1.x == model) + (iv1.y == model) + (iv1.z == model) + (iv1.w == model);
  int inc = cnt;
#pragma unroll
  for (int d = 1; d < 64; d <<= 1) {
    int u = __shfl_up(inc, d);
    if (lane >= d) inc += u;
  }
  if (lane == 63) wsum[wv] = inc;
  barrier_lds_only();                // RAW-BAR-1: wsum + rid(-1) committed
  int wpre = 0, total = 0;
#pragma unroll
  for (int j = 0; j < 16; ++j) {
    int sj = wsum[j];
    total += sj;
    if (j < wv) wpre += sj;
  }
  const int start = s * BM;
  if (start >= total) return;        // block-uniform (only s==1 can exit;
                                     // those blocks issued no DMA)
  if (s == 1) { W_DMA(0, 0) W_DMA(1, 1) }

  int off = wpre + inc - cnt - start;
  {
    int n0 = t * 8;
    if (iv0.x == model) { if ((unsigned)off < BM) rid[off] = n0 + 0; ++off; }
    if (iv0.y == model) { if ((unsigned)off < BM) rid[off] = n0 + 1; ++off; }
    if (iv0.z == model) { if ((unsigned)off < BM) rid[off] = n0 + 2; ++off; }
    if (iv0.w == model) { if ((unsigned)off < BM) rid[off] = n0 + 3; ++off; }
    if (iv1.x == model) { if ((unsigned)off < BM) rid[off] = n0 + 4; ++off; }
    if (iv1.y == model) { if ((unsigned)off < BM) rid[off] = n0 + 5; ++off; }
    if (iv1.z == model) { if ((unsigned)off < BM) rid[off] = n0 + 6; ++off; }
    if (iv1.w == model) { if ((unsigned)off < BM) rid[off] = n0 + 7; ++off; }
  }
  barrier_lds_only();                // RAW-BAR-2: rid ready (DMA untouched)

  // ---- x DMA: per-lane gathered global src, wave-linear LDS dest ----
  // thread covers slots t and t+1024 of (128 rows x 16 chunks);
  // wave wv -> rows [wv*4, wv*4+4) (j=0) and [64+wv*4, ..) (j=1)
  const int   r_0 = wv * 4 + l_r;
  const int   r_1 = 64 + wv * 4 + l_r;
  const int   sr0 = rid[r_0];
  const int   sr1 = rid[r_1];
  const float* xb0 = x + (size_t)(sr0 < 0 ? 0 : sr0) * IN_F
                       + ((l_c ^ (r_0 & 7)) << 2);
  const float* xb1 = x + (size_t)(sr1 < 0 ? 0 : sr1) * IN_F
                       + ((l_c ^ (r_1 & 7)) << 2);
#define X_DMA(q, buf)                                                        \
  {                                                                          \
    dma16(xb0 + (q) * 64, &x_lds[buf][wv * 4][0]);                           \
    dma16(xb1 + (q) * 64, &x_lds[buf][64 + wv * 4][0]);                      \
  }

  X_DMA(0, 0)                        // x q0+q1 in flight immediately
  X_DMA(1, 1)

  // wave tile coords + bias (issued while DMAs fly)
  const int wm   = (wv & 3) * 32;    // 4x4 wave grid of 32x32 tiles
  const int wn   = (wv >> 2) * 32;
  const int col  = lane & 15;
  const int quad = lane >> 4;
  float bv[2];
  const float* bp = bias_g + model * OUT_F + i0 + wn + col;
#pragma unroll
  for (int nt = 0; nt < 2; ++nt) bv[nt] = bp[nt * 16];

  __syncthreads();                   // B1: full drain = all q0,q1 DMA ready

  f32x4 acc[2][2];                   // bias folded into acc init
#pragma unroll
  for (int mt = 0; mt < 2; ++mt)
#pragma unroll
    for (int nt = 0; nt < 2; ++nt)
      acc[mt][nt] = (f32x4){bv[nt], bv[nt], bv[nt], bv[nt]};

  // one quarter = 2 k-steps; A and B frags both f32+XOR-swizzle+pack8
#define MFMA_QUARTER(buf, ks0)                                               \
  {                                                                          \
    _Pragma("unroll")                                                        \
    for (int kk = 0; kk < 2; ++kk) {                                         \
      const int ch0 = kk * 8 + quad * 2;                                     \
      bf16x8 af[2], bfr[2];                                                  \
      _Pragma("unroll")                                                      \
      for (int mt = 0; mt < 2; ++mt) {                                       \
        const int Ra  = wm + mt * 16 + col;                                  \
        const int swa = Ra & 7;                                              \
        float4 a0 = *(const float4*)&x_lds[buf][Ra][((ch0)     ^ swa) << 2]; \
        float4 a1 = *(const float4*)&x_lds[buf][Ra][((ch0 + 1) ^ swa) << 2]; \
        af[mt] = pack8(a0, a1);                                              \
      }                                                                      \
      _Pragma("unroll")                                                      \
      for (int nt = 0; nt < 2; ++nt) {                                       \
        const int R  = wn + nt * 16 + col;                                   \
        const int sw = R & 7;                                                \
        float4 f0 = *(const float4*)&w_lds[buf][R][((ch0)     ^ sw) << 2];   \
        float4 f1 = *(const float4*)&w_lds[buf][R][((ch0 + 1) ^ sw) << 2];   \
        bfr[nt] = pack8(f0, f1);                                             \
      }                                                                      \
      _Pragma("unroll")                                                      \
      for (int mt = 0; mt < 2; ++mt)                                         \
        _Pragma("unroll")                                                    \
        for (int nt = 0; nt < 2; ++nt)                                       \
          acc[mt][nt] = __builtin_amdgcn_mfma_f32_16x16x32_bf16(             \
              af[mt], bfr[nt], acc[mt][nt], 0, 0, 0);                        \
    }                                                                        \
  }

  MFMA_QUARTER(0, 0)                 // q0
  __syncthreads();                   // B2: buf0 reads done
  W_DMA(2, 0) X_DMA(2, 0)            // refill buf0 (overlaps q1 mfma)
  MFMA_QUARTER(1, 2)                 // q1
  __syncthreads();                   // B3: drains q2 DMA; buf1 reads done
  W_DMA(3, 1) X_DMA(3, 1)            // refill buf1 (overlaps q2 mfma)
  MFMA_QUARTER(0, 4)                 // q2
  __syncthreads();                   // B4: drains q3 DMA
  MFMA_QUARTER(1, 6)                 // q3

  // ---- epilogue: relu + scatter by sample id ----
#pragma unroll
  for (int mt = 0; mt < 2; ++mt) {
#pragma unroll
    for (int reg = 0; reg < 4; ++reg) {
      const int mm = wm + mt * 16 + quad * 4 + reg;   // C/D: row = quad*4+reg
      const int sle = rid[mm];
      if (sle >= 0) {
        float* orow = out + (size_t)sle * OUT_F + i0 + wn + col;
#pragma unroll
        for (int nt = 0; nt < 2; ++nt)
          orow[nt * 16] = fmaxf(acc[mt][nt][reg], 0.0f);
      }
    }
  }
#undef W_DMA
#undef X_DMA
#undef MFMA_QUARTER
}

extern "C" void kernel_launch(void* const* d_in, const int* in_sizes, int n_in,
                              void* d_out, int out_size, void* d_ws, size_t ws_size,
                              hipStream_t stream) {
  const float* x    = (const float*)d_in[0];
  const int*   idxs = (const int*)d_in[1];
  const float* w    = (const float*)d_in[2];
  const float* b    = (const float*)d_in[3];
  float* out = (float*)d_out;
  (void)d_ws; (void)ws_size;

  fused_kernel<<<N_MODELS * 4, 1024, 0, stream>>>(x, idxs, w, b, out);
}